// Round 6
// baseline (458.930 us; speedup 1.0000x reference)
//
#include <hip/hip_runtime.h>
#include <stdint.h>

#define N_NODES 8192
#define DIM 256

typedef __attribute__((ext_vector_type(8))) __bf16 bf16x8;
typedef __attribute__((ext_vector_type(4))) float f32x4;

__device__ __forceinline__ unsigned short f2bf(float f) {
  unsigned u = __builtin_bit_cast(unsigned, f);
  u += 0x7fffu + ((u >> 16) & 1u);
  return (unsigned short)(u >> 16);
}
__device__ __forceinline__ float bf2f(unsigned short h) {
  return __builtin_bit_cast(float, (unsigned)h << 16);
}
__device__ __forceinline__ unsigned pack2(float a, float b) {
  return (unsigned)f2bf(a) | ((unsigned)f2bf(b) << 16);
}

// global -> LDS direct (16B/lane). LDS dest linear; swizzle on GLOBAL source.
#define GLD16(g, l)                                                  \
  __builtin_amdgcn_global_load_lds(                                  \
      (const __attribute__((address_space(1))) void*)(g),            \
      (__attribute__((address_space(3))) void*)(l), 16, 0, 0)

#define WAITV(N) asm volatile("s_waitcnt vmcnt(" #N ")" ::: "memory")

// ---------------------------------------------------------------------------
// Kernel 1 (fused, block-specialized):
//   blocks [0,256):      support u = x @ W^T -> uT bf16 [n][j], urm bf16 [j][n]
//   blocks [256, 8448):  rowsum dinv[i] = rsqrt(sum_j adj[i,j] + 1)
//                        AND adjb = bf16(adj)  (reuses the same read)
// ---------------------------------------------------------------------------
__global__ __launch_bounds__(256) void fused_pre_kernel(
    const float* __restrict__ adj, const float* __restrict__ x,
    const float* __restrict__ W, float* __restrict__ dinv,
    unsigned short* __restrict__ uT, unsigned short* __restrict__ urm,
    unsigned short* __restrict__ adjb) {
  __shared__ float4 xs[32 * 64];
  __shared__ float red[4];
  int tid = threadIdx.x;

  if (blockIdx.x >= 256) {
    // ---- rowsum + bf16-convert branch ----
    int row = blockIdx.x - 256;
    const float4* r = (const float4*)(adj + (size_t)row * N_NODES);
    uint2* ab = (uint2*)(adjb + (size_t)row * N_NODES);
    float s = 0.f;
#pragma unroll
    for (int it = 0; it < 8; ++it) {
      float4 v = r[tid + it * 256];
      s += (v.x + v.y) + (v.z + v.w);
      uint2 w;
      w.x = pack2(v.x, v.y);
      w.y = pack2(v.z, v.w);
      ab[tid + it * 256] = w;
    }
#pragma unroll
    for (int off = 32; off > 0; off >>= 1) s += __shfl_down(s, off);
    if ((tid & 63) == 0) red[tid >> 6] = s;
    __syncthreads();
    if (tid == 0) {
      float tot = red[0] + red[1] + red[2] + red[3] + 1.0f;
      dinv[row] = rsqrtf(tot);
    }
    return;
  }

  // ---- support branch: u[j,n] = sum_c x[j,c] * W[n,c] ----
  int j0 = blockIdx.x * 32;
  const float4* xg = (const float4*)(x + (size_t)j0 * DIM);
#pragma unroll
  for (int it = 0; it < 8; ++it) xs[tid + it * 256] = xg[tid + it * 256];
  __syncthreads();

  int n = tid;
  float acc[32];
#pragma unroll
  for (int j = 0; j < 32; ++j) acc[j] = 0.f;
  const float4* wrow = (const float4*)(W + (size_t)n * DIM);
#pragma unroll 1
  for (int cc = 0; cc < 4; ++cc) {
    float4 wr[16];
#pragma unroll
    for (int m = 0; m < 16; ++m) wr[m] = wrow[cc * 16 + m];
#pragma unroll
    for (int j = 0; j < 32; ++j) {
      float s = 0.f;
#pragma unroll
      for (int m = 0; m < 16; ++m) {
        float4 xv = xs[j * 64 + cc * 16 + m];  // LDS broadcast
        s += xv.x * wr[m].x + xv.y * wr[m].y + xv.z * wr[m].z + xv.w * wr[m].w;
      }
      acc[j] += s;
    }
  }
  size_t nrow = (size_t)n * N_NODES;
#pragma unroll
  for (int j = 0; j < 32; ++j) {
    unsigned short b = f2bf(acc[j]);
    uT[nrow + j0 + j] = b;                  // [n][j] bf16 (pre-scale B)
    urm[(size_t)(j0 + j) * DIM + n] = b;    // [j][n] — epilogue +I term
  }
}

// ---------------------------------------------------------------------------
// Kernel 2a: vT[n][j] = bf16( u[n][j] * dinv[j] )  (folds D^{-1/2} into B)
// ---------------------------------------------------------------------------
__global__ __launch_bounds__(256) void scale_kernel(
    const unsigned short* __restrict__ uT, const float* __restrict__ dinv,
    unsigned short* __restrict__ vT) {
  size_t idx = ((size_t)blockIdx.x * 256 + threadIdx.x) * 8;
  int j = (int)(idx & (N_NODES - 1));
  uint4 uv = *(const uint4*)(uT + idx);
  float4 d0 = *(const float4*)(dinv + j);
  float4 d1 = *(const float4*)(dinv + j + 4);
  float f0 = bf2f((unsigned short)(uv.x & 0xffff)) * d0.x;
  float f1 = bf2f((unsigned short)(uv.x >> 16)) * d0.y;
  float f2 = bf2f((unsigned short)(uv.y & 0xffff)) * d0.z;
  float f3 = bf2f((unsigned short)(uv.y >> 16)) * d0.w;
  float f4 = bf2f((unsigned short)(uv.z & 0xffff)) * d1.x;
  float f5 = bf2f((unsigned short)(uv.z >> 16)) * d1.y;
  float f6 = bf2f((unsigned short)(uv.w & 0xffff)) * d1.z;
  float f7 = bf2f((unsigned short)(uv.w >> 16)) * d1.w;
  uint4 o;
  o.x = pack2(f0, f1);
  o.y = pack2(f2, f3);
  o.z = pack2(f4, f5);
  o.w = pack2(f6, f7);
  *(uint4*)(vT + idx) = o;
}

// ---------------------------------------------------------------------------
// Kernel 2: bf16 split-K GEMM  part[s][i,n] = sum_j adjb[i,j]*vT[n,j]
// Tile 64(M) x 256(N full) x BK=32, 4 waves (each 64x64 = 4x4 frags of
// 16x16x32 bf16). 4-BUFFER RING, prefetch depth 3, COUNTED vmcnt (T4):
//   stage(it+3)                 // 5 gload_lds, not waited
//   s_waitcnt vmcnt(15)         // drain ONLY buf[it]'s 5 oldest; 15 in flight
//   s_barrier                   // all waves' buf[it] loads complete -> ready
//   8 x ds_read_b128 + 16 MFMA  // compute buf[it]
//   sched_barrier(0); s_barrier // all waves done reading before reuse
// Never vmcnt(0) in the main loop -> loads have 3 iters (~750+ cyc) to land.
// LDS rows 64 B (4 x 16B chunks); chunk ^= (row>>1)&3 swizzle on the GLOBAL
// source, mirrored on the ds_read offset -> 2 lanes/bank (free).
// 80 KiB LDS = 4 x (A 4K | B 16K) -> exactly 2 blocks/CU (grid 512 = 2/CU).
// MFMA K-order identical to R5 kernel -> bit-identical partials.
// ---------------------------------------------------------------------------
__global__ __launch_bounds__(256) void gemm_kernel(
    const unsigned short* __restrict__ adjb, const unsigned short* __restrict__ vT,
    unsigned short* __restrict__ part, int KC) {
  __shared__ __align__(16) unsigned char smem[81920];  // 4 x 20 KiB
  float* Cs = (float*)smem;  // epilogue reuse (32 KiB)

  int tid = threadIdx.x;
  int lane = tid & 63, wave = tid >> 6;
  size_t i0 = (size_t)blockIdx.x * 64;
  int kbase = blockIdx.y * KC;

  // staging map: row = tid>>2, chunk = tid&3; fetch global 16B chunk
  // (chunk ^ ((row>>1)&3)) -> LDS stays linear (dest = tid*16).
  int rA = tid >> 2;
  int seg = (tid & 3) ^ ((rA >> 1) & 3);
  const unsigned short* gA = adjb + (i0 + rA) * (size_t)N_NODES + kbase + seg * 8;
  const unsigned short* gB = vT + (size_t)rA * N_NODES + kbase + seg * 8;

  f32x4 acc[4][4];
#pragma unroll
  for (int mf = 0; mf < 4; ++mf)
#pragma unroll
    for (int nf = 0; nf < 4; ++nf) acc[mf][nf] = (f32x4){0.f, 0.f, 0.f, 0.f};

  // fragment read: row r holds global chunk c at LDS chunk c^((r>>1)&3);
  // lane wants chunk akq of row (frag*16 + arow); (row>>1)&3 invariant in frag.
  int arow = lane & 15, akq = lane >> 4;
  int xoff = ((akq ^ ((arow >> 1) & 3)) << 4);  // byte offset within 64-B row

  auto stage = [&](int b, int k) {  // k in shorts
    unsigned char* base = smem + b * 20480;
    GLD16(gA + k, base + tid * 16);
#pragma unroll
    for (int tt = 0; tt < 4; ++tt)
      GLD16(gB + (size_t)(tt * 64) * N_NODES + k, base + 4096 + tt * 4096 + tid * 16);
  };

  int nIter = KC >> 5;  // 64
  stage(0, 0);
  stage(1, 32);
  stage(2, 64);

  for (int it = 0; it < nIter; ++it) {
    if (it + 3 < nIter) {
      stage((it + 3) & 3, (it + 3) << 5);
      WAITV(15);  // drain own buf[it] loads; keep 15 in flight
    } else {
      WAITV(0);   // tail drain
    }
    __builtin_amdgcn_s_barrier();  // buf[it] ready across all waves

    const unsigned char* base = smem + (it & 3) * 20480;
    const unsigned char* Bw = base + 4096 + wave * 4096;
    bf16x8 a[4], b[4];
#pragma unroll
    for (int mf = 0; mf < 4; ++mf)
      a[mf] = *reinterpret_cast<const bf16x8*>(base + (mf * 16 + arow) * 64 + xoff);
#pragma unroll
    for (int nf = 0; nf < 4; ++nf)
      b[nf] = *reinterpret_cast<const bf16x8*>(Bw + (nf * 16 + arow) * 64 + xoff);
#pragma unroll
    for (int mf = 0; mf < 4; ++mf)
#pragma unroll
      for (int nf = 0; nf < 4; ++nf)
        acc[mf][nf] =
            __builtin_amdgcn_mfma_f32_16x16x32_bf16(a[mf], b[nf], acc[mf][nf], 0, 0, 0);

    __builtin_amdgcn_sched_barrier(0);
    __builtin_amdgcn_s_barrier();  // reads done before buf reuse (no vm drain)
  }

  // ---- epilogue: stage C through LDS, store bf16 partial rows ----
  unsigned short* pb = part + (size_t)blockIdx.y * ((size_t)N_NODES * DIM);
  int crow = (lane >> 4) * 4;  // C/D layout: col=lane&15, row=(lane>>4)*4+reg
  int ccol = lane & 15;
#pragma unroll
  for (int p = 0; p < 2; ++p) {  // rows [p*32, p*32+32)
    __syncthreads();             // prev pass / main-loop LDS reads done
#pragma unroll
    for (int mf2 = 0; mf2 < 2; ++mf2) {
      int mf = p * 2 + mf2;
#pragma unroll
      for (int nf = 0; nf < 4; ++nf)
#pragma unroll
        for (int r = 0; r < 4; ++r)
          Cs[(mf2 * 16 + crow + r) * 256 + wave * 64 + nf * 16 + ccol] = acc[mf][nf][r];
    }
    __syncthreads();
#pragma unroll
    for (int it = 0; it < 8; ++it) {
      int f = tid + it * 256;
      int row = f >> 6, c4 = f & 63;
      const float4 vv = *(const float4*)(Cs + row * 256 + c4 * 4);
      uint2 w;
      w.x = pack2(vv.x, vv.y);
      w.y = pack2(vv.z, vv.w);
      *(uint2*)(pb + (i0 + p * 32 + row) * (size_t)DIM + c4 * 4) = w;
    }
  }
}

// ---------------------------------------------------------------------------
// Kernel 3: out[i,k] = relu(d_i * sum_s part[s][i,k] + d_i^2 * u[i,k])
// ---------------------------------------------------------------------------
__global__ __launch_bounds__(256) void reduce_kernel(
    const unsigned short* __restrict__ part, const unsigned short* __restrict__ urm,
    const float* __restrict__ dinv, float* __restrict__ out, int S) {
  size_t idx = ((size_t)blockIdx.x * 256 + threadIdx.x) * 4;
  int i = (int)(idx >> 8);
  float4 v = {0.f, 0.f, 0.f, 0.f};
  for (int s = 0; s < S; ++s) {
    uint2 pv = *(const uint2*)(part + (size_t)s * ((size_t)N_NODES * DIM) + idx);
    v.x += bf2f((unsigned short)(pv.x & 0xffff));
    v.y += bf2f((unsigned short)(pv.x >> 16));
    v.z += bf2f((unsigned short)(pv.y & 0xffff));
    v.w += bf2f((unsigned short)(pv.y >> 16));
  }
  ushort4 t = *(const ushort4*)(urm + idx);
  float d = dinv[i];
  float dd = d * d;
  float4 o;
  o.x = fmaxf(0.f, d * v.x + dd * bf2f(t.x));
  o.y = fmaxf(0.f, d * v.y + dd * bf2f(t.y));
  o.z = fmaxf(0.f, d * v.z + dd * bf2f(t.z));
  o.w = fmaxf(0.f, d * v.w + dd * bf2f(t.w));
  *(float4*)(out + idx) = o;
}

// ---------------------------------------------------------------------------
extern "C" void kernel_launch(void* const* d_in, const int* in_sizes, int n_in,
                              void* d_out, int out_size, void* d_ws, size_t ws_size,
                              hipStream_t stream) {
  const float* x = (const float*)d_in[0];
  const float* adj = (const float*)d_in[1];
  const float* W = (const float*)d_in[2];
  float* out = (float*)d_out;
  char* ws = (char*)d_ws;

  // ws: dinv 32K | uT 4M | urm 4M | vT 4M | adjb 128M | part S x 4M (bf16)
  size_t oUT = 32768;
  size_t oURM = oUT + (size_t)DIM * N_NODES * 2;
  size_t oVT = oURM + (size_t)N_NODES * DIM * 2;
  size_t oADJ = oVT + (size_t)DIM * N_NODES * 2;
  size_t oPART = oADJ + (size_t)N_NODES * N_NODES * 2;
  size_t pbytes = (size_t)N_NODES * DIM * 2;

  float* dinv = (float*)ws;
  unsigned short* uT = (unsigned short*)(ws + oUT);
  unsigned short* urm = (unsigned short*)(ws + oURM);
  unsigned short* vT = (unsigned short*)(ws + oVT);
  unsigned short* adjb = (unsigned short*)(ws + oADJ);

  // S=4: 512 GEMM blocks = 2/CU (matches 80-KiB-LDS occupancy).
  int S;
  unsigned short* part;
  if (oPART + 4 * pbytes <= ws_size) { S = 4; part = (unsigned short*)(ws + oPART); }
  else if (oPART + 2 * pbytes <= ws_size) { S = 2; part = (unsigned short*)(ws + oPART); }
  else { S = 1; part = (unsigned short*)(ws + oPART); }

  fused_pre_kernel<<<256 + N_NODES, 256, 0, stream>>>(adj, x, W, dinv, uT, urm, adjb);
  scale_kernel<<<(N_NODES * DIM) / (8 * 256), 256, 0, stream>>>(uT, dinv, vT);
  gemm_kernel<<<dim3(N_NODES / 64, S), 256, 0, stream>>>(adjb, vT, part, N_NODES / S);
  reduce_kernel<<<(N_NODES * DIM) / 1024, 256, 0, stream>>>(part, urm, dinv, out, S);
}

// Round 7
// 451.756 us; speedup vs baseline: 1.0159x; 1.0159x over previous
//
#include <hip/hip_runtime.h>
#include <stdint.h>

#define N_NODES 8192
#define DIM 256

typedef __attribute__((ext_vector_type(8))) __bf16 bf16x8;
typedef __attribute__((ext_vector_type(4))) float f32x4;

__device__ __forceinline__ unsigned short f2bf(float f) {
  unsigned u = __builtin_bit_cast(unsigned, f);
  u += 0x7fffu + ((u >> 16) & 1u);
  return (unsigned short)(u >> 16);
}
__device__ __forceinline__ float bf2f(unsigned short h) {
  return __builtin_bit_cast(float, (unsigned)h << 16);
}
__device__ __forceinline__ unsigned pack2(float a, float b) {
  return (unsigned)f2bf(a) | ((unsigned)f2bf(b) << 16);
}

// global -> LDS direct (16B/lane). LDS dest linear; swizzle on GLOBAL source.
#define GLD16(g, l)                                                  \
  __builtin_amdgcn_global_load_lds(                                  \
      (const __attribute__((address_space(1))) void*)(g),            \
      (__attribute__((address_space(3))) void*)(l), 16, 0, 0)

// ---------------------------------------------------------------------------
// Kernel 1 (fused, block-specialized):
//   blocks [0,256):      support u = x @ W^T -> uT bf16 [n][j], urm bf16 [j][n]
//   blocks [256, 8448):  rowsum dinv[i] = rsqrt(sum_j adj[i,j] + 1)
//                        AND adjb = bf16(adj)  (reuses the same read)
// ---------------------------------------------------------------------------
__global__ __launch_bounds__(256) void fused_pre_kernel(
    const float* __restrict__ adj, const float* __restrict__ x,
    const float* __restrict__ W, float* __restrict__ dinv,
    unsigned short* __restrict__ uT, unsigned short* __restrict__ urm,
    unsigned short* __restrict__ adjb) {
  __shared__ float4 xs[32 * 64];
  __shared__ float red[4];
  int tid = threadIdx.x;

  if (blockIdx.x >= 256) {
    // ---- rowsum + bf16-convert branch ----
    int row = blockIdx.x - 256;
    const float4* r = (const float4*)(adj + (size_t)row * N_NODES);
    uint2* ab = (uint2*)(adjb + (size_t)row * N_NODES);
    float s = 0.f;
#pragma unroll
    for (int it = 0; it < 8; ++it) {
      float4 v = r[tid + it * 256];
      s += (v.x + v.y) + (v.z + v.w);
      uint2 w;
      w.x = pack2(v.x, v.y);
      w.y = pack2(v.z, v.w);
      ab[tid + it * 256] = w;
    }
#pragma unroll
    for (int off = 32; off > 0; off >>= 1) s += __shfl_down(s, off);
    if ((tid & 63) == 0) red[tid >> 6] = s;
    __syncthreads();
    if (tid == 0) {
      float tot = red[0] + red[1] + red[2] + red[3] + 1.0f;
      dinv[row] = rsqrtf(tot);
    }
    return;
  }

  // ---- support branch: u[j,n] = sum_c x[j,c] * W[n,c] ----
  int j0 = blockIdx.x * 32;
  const float4* xg = (const float4*)(x + (size_t)j0 * DIM);
#pragma unroll
  for (int it = 0; it < 8; ++it) xs[tid + it * 256] = xg[tid + it * 256];
  __syncthreads();

  int n = tid;
  float acc[32];
#pragma unroll
  for (int j = 0; j < 32; ++j) acc[j] = 0.f;
  const float4* wrow = (const float4*)(W + (size_t)n * DIM);
#pragma unroll 1
  for (int cc = 0; cc < 4; ++cc) {
    float4 wr[16];
#pragma unroll
    for (int m = 0; m < 16; ++m) wr[m] = wrow[cc * 16 + m];
#pragma unroll
    for (int j = 0; j < 32; ++j) {
      float s = 0.f;
#pragma unroll
      for (int m = 0; m < 16; ++m) {
        float4 xv = xs[j * 64 + cc * 16 + m];  // LDS broadcast
        s += xv.x * wr[m].x + xv.y * wr[m].y + xv.z * wr[m].z + xv.w * wr[m].w;
      }
      acc[j] += s;
    }
  }
  size_t nrow = (size_t)n * N_NODES;
#pragma unroll
  for (int j = 0; j < 32; ++j) {
    unsigned short b = f2bf(acc[j]);
    uT[nrow + j0 + j] = b;                  // [n][j] bf16 (pre-scale B)
    urm[(size_t)(j0 + j) * DIM + n] = b;    // [j][n] — epilogue +I term
  }
}

// ---------------------------------------------------------------------------
// Kernel 2a: vT[n][j] = bf16( u[n][j] * dinv[j] )  (folds D^{-1/2} into B)
// ---------------------------------------------------------------------------
__global__ __launch_bounds__(256) void scale_kernel(
    const unsigned short* __restrict__ uT, const float* __restrict__ dinv,
    unsigned short* __restrict__ vT) {
  size_t idx = ((size_t)blockIdx.x * 256 + threadIdx.x) * 8;
  int j = (int)(idx & (N_NODES - 1));
  uint4 uv = *(const uint4*)(uT + idx);
  float4 d0 = *(const float4*)(dinv + j);
  float4 d1 = *(const float4*)(dinv + j + 4);
  float f0 = bf2f((unsigned short)(uv.x & 0xffff)) * d0.x;
  float f1 = bf2f((unsigned short)(uv.x >> 16)) * d0.y;
  float f2 = bf2f((unsigned short)(uv.y & 0xffff)) * d0.z;
  float f3 = bf2f((unsigned short)(uv.y >> 16)) * d0.w;
  float f4 = bf2f((unsigned short)(uv.z & 0xffff)) * d1.x;
  float f5 = bf2f((unsigned short)(uv.z >> 16)) * d1.y;
  float f6 = bf2f((unsigned short)(uv.w & 0xffff)) * d1.z;
  float f7 = bf2f((unsigned short)(uv.w >> 16)) * d1.w;
  uint4 o;
  o.x = pack2(f0, f1);
  o.y = pack2(f2, f3);
  o.z = pack2(f4, f5);
  o.w = pack2(f6, f7);
  *(uint4*)(vT + idx) = o;
}

// ---------------------------------------------------------------------------
// Kernel 2: bf16 split-K GEMM  part[s][i,n] = sum_j adjb[i,j]*vT[n,j]
// Tile 64(M) x 256(N full) x BK=64, 4 waves (each 64x64 = 4x4 frags of
// 16x16x32 bf16, K-unroll 2). 2-phase double-buffer: stage(next) issued
// before compute, single barrier/iter. LDS rows 128 B (8 x 16B chunks);
// chunk ^= (row&7) swizzle applied on the GLOBAL source and mirrored on the
// ds_read side -> conflict-free ds_read_b128. 80 KiB LDS, 2 blocks/CU.
// Partials stored bf16 (halves partial traffic vs f32).
// [R6 lesson: deeper ring + counted vmcnt at BK=32 REGRESSED (−6 µs) —
//  cross-wave/cross-block overlap already covers load latency here.]
// ---------------------------------------------------------------------------
__global__ __launch_bounds__(256) void gemm_kernel(
    const unsigned short* __restrict__ adjb, const unsigned short* __restrict__ vT,
    unsigned short* __restrict__ part, int KC) {
  __shared__ __align__(16) unsigned short smem[40960];  // 80 KiB
  float* Cs = (float*)smem;  // epilogue reuse (32 KiB)

  int tid = threadIdx.x;
  int lane = tid & 63, wave = tid >> 6;
  size_t i0 = (size_t)blockIdx.x * 64;
  int kbase = blockIdx.y * KC;

  // staging map: row = tid>>3 (+32 per extra issue), chunk = tid&7;
  // fetch global chunk (chunk ^ (row&7)) -> LDS stays linear.
  int rowA = tid >> 3;
  int seg = (tid & 7) ^ (rowA & 7);
  const unsigned short* gA = adjb + (i0 + rowA) * (size_t)N_NODES + kbase + seg * 8;
  const unsigned short* gB = vT + (size_t)rowA * N_NODES + kbase + seg * 8;

  f32x4 acc[4][4];
#pragma unroll
  for (int mf = 0; mf < 4; ++mf)
#pragma unroll
    for (int nf = 0; nf < 4; ++nf) acc[mf][nf] = (f32x4){0.f, 0.f, 0.f, 0.f};

  // fragment read offsets (shorts), swizzle-mirrored: chunk = (kk*4+akq)^(row&7)
  int arow = lane & 15, akq = lane >> 4;
  int a7 = arow & 7;
  int off0 = arow * 64 + ((akq ^ a7) << 3);        // kk=0
  int off1 = arow * 64 + (((akq + 4) ^ a7) << 3);  // kk=1

  auto stage = [&](int buf, int k) {
    unsigned short* lA = smem + buf * 20480 + tid * 8;
    unsigned short* lB = lA + 4096;
    GLD16(gA + k, lA);
    GLD16(gA + (size_t)32 * N_NODES + k, lA + 2048);
#pragma unroll
    for (int t = 0; t < 8; ++t)
      GLD16(gB + (size_t)(t * 32) * N_NODES + k, lB + t * 2048);
  };

  stage(0, 0);
  __syncthreads();

  int nIter = KC >> 6;
  for (int it = 0; it < nIter; ++it) {
    int cur = it & 1;
    if (it + 1 < nIter) stage(cur ^ 1, (it + 1) << 6);  // issue early, no wait

    const unsigned short* Al = smem + cur * 20480;
    const unsigned short* Bw = Al + 4096 + wave * 4096;
    bf16x8 a0[4], a1[4], b0[4], b1[4];
#pragma unroll
    for (int mf = 0; mf < 4; ++mf) {
      a0[mf] = *reinterpret_cast<const bf16x8*>(&Al[mf * 1024 + off0]);
      a1[mf] = *reinterpret_cast<const bf16x8*>(&Al[mf * 1024 + off1]);
    }
#pragma unroll
    for (int nf = 0; nf < 4; ++nf) {
      b0[nf] = *reinterpret_cast<const bf16x8*>(&Bw[nf * 1024 + off0]);
      b1[nf] = *reinterpret_cast<const bf16x8*>(&Bw[nf * 1024 + off1]);
    }
#pragma unroll
    for (int mf = 0; mf < 4; ++mf)
#pragma unroll
      for (int nf = 0; nf < 4; ++nf) {
        acc[mf][nf] =
            __builtin_amdgcn_mfma_f32_16x16x32_bf16(a0[mf], b0[nf], acc[mf][nf], 0, 0, 0);
        acc[mf][nf] =
            __builtin_amdgcn_mfma_f32_16x16x32_bf16(a1[mf], b1[nf], acc[mf][nf], 0, 0, 0);
      }
    __syncthreads();  // loads for buf^1 already landed; LDS reuse
  }

  // ---- epilogue: stage C through LDS, store bf16 partial rows ----
  unsigned short* pb = part + (size_t)blockIdx.y * ((size_t)N_NODES * DIM);
  int crow = (lane >> 4) * 4;  // C/D layout: col=lane&15, row=(lane>>4)*4+reg
  int ccol = lane & 15;
#pragma unroll
  for (int p = 0; p < 2; ++p) {  // rows [p*32, p*32+32)
    if (p) __syncthreads();
#pragma unroll
    for (int mf2 = 0; mf2 < 2; ++mf2) {
      int mf = p * 2 + mf2;
#pragma unroll
      for (int nf = 0; nf < 4; ++nf)
#pragma unroll
        for (int r = 0; r < 4; ++r)
          Cs[(mf2 * 16 + crow + r) * 256 + wave * 64 + nf * 16 + ccol] = acc[mf][nf][r];
    }
    __syncthreads();
#pragma unroll
    for (int it = 0; it < 8; ++it) {
      int f = tid + it * 256;
      int row = f >> 6, c4 = f & 63;
      const float4 vv = *(const float4*)(Cs + row * 256 + c4 * 4);
      uint2 w;
      w.x = pack2(vv.x, vv.y);
      w.y = pack2(vv.z, vv.w);
      *(uint2*)(pb + (i0 + p * 32 + row) * (size_t)DIM + c4 * 4) = w;
    }
  }
}

// ---------------------------------------------------------------------------
// Kernel 3: out[i,k] = relu(d_i * sum_s part[s][i,k] + d_i^2 * u[i,k])
// ---------------------------------------------------------------------------
__global__ __launch_bounds__(256) void reduce_kernel(
    const unsigned short* __restrict__ part, const unsigned short* __restrict__ urm,
    const float* __restrict__ dinv, float* __restrict__ out, int S) {
  size_t idx = ((size_t)blockIdx.x * 256 + threadIdx.x) * 4;
  int i = (int)(idx >> 8);
  float4 v = {0.f, 0.f, 0.f, 0.f};
  for (int s = 0; s < S; ++s) {
    uint2 pv = *(const uint2*)(part + (size_t)s * ((size_t)N_NODES * DIM) + idx);
    v.x += bf2f((unsigned short)(pv.x & 0xffff));
    v.y += bf2f((unsigned short)(pv.x >> 16));
    v.z += bf2f((unsigned short)(pv.y & 0xffff));
    v.w += bf2f((unsigned short)(pv.y >> 16));
  }
  ushort4 t = *(const ushort4*)(urm + idx);
  float d = dinv[i];
  float dd = d * d;
  float4 o;
  o.x = fmaxf(0.f, d * v.x + dd * bf2f(t.x));
  o.y = fmaxf(0.f, d * v.y + dd * bf2f(t.y));
  o.z = fmaxf(0.f, d * v.z + dd * bf2f(t.z));
  o.w = fmaxf(0.f, d * v.w + dd * bf2f(t.w));
  *(float4*)(out + idx) = o;
}

// ---------------------------------------------------------------------------
extern "C" void kernel_launch(void* const* d_in, const int* in_sizes, int n_in,
                              void* d_out, int out_size, void* d_ws, size_t ws_size,
                              hipStream_t stream) {
  const float* x = (const float*)d_in[0];
  const float* adj = (const float*)d_in[1];
  const float* W = (const float*)d_in[2];
  float* out = (float*)d_out;
  char* ws = (char*)d_ws;

  // ws: dinv 32K | uT 4M | urm 4M | vT 4M | adjb 128M | part S x 4M (bf16)
  size_t oUT = 32768;
  size_t oURM = oUT + (size_t)DIM * N_NODES * 2;
  size_t oVT = oURM + (size_t)N_NODES * DIM * 2;
  size_t oADJ = oVT + (size_t)DIM * N_NODES * 2;
  size_t oPART = oADJ + (size_t)N_NODES * N_NODES * 2;
  size_t pbytes = (size_t)N_NODES * DIM * 2;

  float* dinv = (float*)ws;
  unsigned short* uT = (unsigned short*)(ws + oUT);
  unsigned short* urm = (unsigned short*)(ws + oURM);
  unsigned short* vT = (unsigned short*)(ws + oVT);
  unsigned short* adjb = (unsigned short*)(ws + oADJ);

  // S=4: 512 GEMM blocks = 2/CU (matches 80-KiB-LDS occupancy).
  int S;
  unsigned short* part;
  if (oPART + 4 * pbytes <= ws_size) { S = 4; part = (unsigned short*)(ws + oPART); }
  else if (oPART + 2 * pbytes <= ws_size) { S = 2; part = (unsigned short*)(ws + oPART); }
  else { S = 1; part = (unsigned short*)(ws + oPART); }

  fused_pre_kernel<<<256 + N_NODES, 256, 0, stream>>>(adj, x, W, dinv, uT, urm, adjb);
  scale_kernel<<<(N_NODES * DIM) / (8 * 256), 256, 0, stream>>>(uT, dinv, vT);
  gemm_kernel<<<dim3(N_NODES / 64, S), 256, 0, stream>>>(adjb, vT, part, N_NODES / S);
  reduce_kernel<<<(N_NODES * DIM) / 1024, 256, 0, stream>>>(part, urm, dinv, out, S);
}